// Round 18
// baseline (509.789 us; speedup 1.0000x reference)
//
#include <hip/hip_runtime.h>
#include <hip/hip_cooperative_groups.h>
#include <stdint.h>

namespace cg = cooperative_groups;

#define E_NUM 8
#define CAP 8192
#define NTOK 32768
#define CDIM 384
#define DFF 1536
#define CNT_PAD 64  // ints between counters -> 256B, separate cache lines

#define NBLK 256          // cooperative grid: 1 block/CU guaranteed resident
#define FFN1_TILES 6144   // 512 mglob x 12 n
#define FFN2_TILES 1536   // 512 mglob x 3 n

typedef unsigned short u16;
typedef __attribute__((ext_vector_type(8))) short short8;
typedef __attribute__((ext_vector_type(4))) float f32x4;

__device__ inline u16 f2bf(float f) {
    uint32_t u = __builtin_bit_cast(uint32_t, f);
    u += 0x7fffu + ((u >> 16) & 1u);
    return (u16)(u >> 16);
}

__device__ inline uint32_t pk2(float a, float b) {
    return (uint32_t)f2bf(a) | ((uint32_t)f2bf(b) << 16);
}

__device__ inline void gload_lds16(const void* g, void* l) {
    __builtin_amdgcn_global_load_lds(
        (const __attribute__((address_space(1))) void*)(uintptr_t)g,
        (__attribute__((address_space(3))) void*)(uint32_t)(uintptr_t)l,
        16, 0, 0);
}

__device__ inline void expert_span(const int* __restrict__ cnt, int e,
                                   int& base, int& n_e) {
    base = 0; n_e = 0;
#pragma unroll
    for (int i = 0; i < E_NUM; ++i) {
        int n = min(cnt[i * CNT_PAD], CAP);
        if (i < e) base += (n + 127) & ~127;
        else if (i == e) n_e = n;
    }
}

// ---------------- routing slice: 64 tokens, 512 threads (8 k-segs x 48k) ----
__device__ __forceinline__ void routing_slice(
    int sl, char* smem,
    const float* __restrict__ x, const float* __restrict__ noise,
    const float* __restrict__ w_route, const float* __restrict__ b_route,
    const float* __restrict__ w_noise, const float* __restrict__ b_noise,
    int* __restrict__ cnt, int* __restrict__ list, float* __restrict__ gate,
    u16* __restrict__ xbf)
{
    float* xs   = (float*)smem;             // 64 * 68 floats = 17.4 KB
    float* part = (float*)(smem + 32768);   // 8*64*16 floats = 32 KB
    int tid = threadIdx.x;
    int lane = tid & 63;
    int seg = __builtin_amdgcn_readfirstlane(tid >> 6);  // 0..7, SGPR-uniform
    int tok = tid & 63;
    int t0 = sl * 64;
    int srow = tid >> 3;          // 0..63
    int scol = (tid & 7) * 8;     // 0..56

    float ar[E_NUM], an[E_NUM];
#pragma unroll
    for (int e = 0; e < E_NUM; ++e) { ar[e] = 0.f; an[e] = 0.f; }

    for (int c = 0; c < CDIM / 64; ++c) {
        __syncthreads();
        const float* xr = x + (size_t)(t0 + srow) * CDIM + c * 64 + scol;
        float4 v0 = *(const float4*)xr;
        float4 v1 = *(const float4*)(xr + 4);
        *(float4*)&xs[srow * 68 + scol]     = v0;
        *(float4*)&xs[srow * 68 + scol + 4] = v1;
        uint2* xo = (uint2*)(xbf + (size_t)(t0 + srow) * CDIM + c * 64 + scol);
        uint2 b0, b1;
        b0.x = pk2(v0.x, v0.y); b0.y = pk2(v0.z, v0.w);
        b1.x = pk2(v1.x, v1.y); b1.y = pk2(v1.z, v1.w);
        xo[0] = b0; xo[1] = b1;
        __syncthreads();
#pragma unroll
        for (int q = 0; q < 2; ++q) {
            float4 xq = *(const float4*)&xs[tok * 68 + seg * 8 + q * 4];
            int kb = c * 64 + seg * 8 + q * 4;   // wave-uniform
#pragma unroll
            for (int jj = 0; jj < 4; ++jj) {
                const float* wrk = w_route + (size_t)(kb + jj) * E_NUM;
                const float* wnk = w_noise + (size_t)(kb + jj) * E_NUM;
                float4 wa = *(const float4*)wrk, wb = *(const float4*)(wrk + 4);
                float4 na = *(const float4*)wnk, nb = *(const float4*)(wnk + 4);
                float xk = (jj == 0) ? xq.x : (jj == 1) ? xq.y : (jj == 2) ? xq.z : xq.w;
                ar[0] += xk * wa.x; ar[1] += xk * wa.y; ar[2] += xk * wa.z; ar[3] += xk * wa.w;
                ar[4] += xk * wb.x; ar[5] += xk * wb.y; ar[6] += xk * wb.z; ar[7] += xk * wb.w;
                an[0] += xk * na.x; an[1] += xk * na.y; an[2] += xk * na.z; an[3] += xk * na.w;
                an[4] += xk * nb.x; an[5] += xk * nb.y; an[6] += xk * nb.z; an[7] += xk * nb.w;
            }
        }
    }
    float* pp = part + (size_t)(seg * 64 + tok) * 16;
    *(f32x4*)&pp[0]  = (f32x4){ar[0], ar[1], ar[2], ar[3]};
    *(f32x4*)&pp[4]  = (f32x4){ar[4], ar[5], ar[6], ar[7]};
    *(f32x4*)&pp[8]  = (f32x4){an[0], an[1], an[2], an[3]};
    *(f32x4*)&pp[12] = (f32x4){an[4], an[5], an[6], an[7]};
    __syncthreads();
    if (seg == 0) {
        int t = t0 + lane;
        float sr[E_NUM], sn[E_NUM];
#pragma unroll
        for (int e = 0; e < E_NUM; ++e) { sr[e] = b_route[e]; sn[e] = b_noise[e]; }
#pragma unroll
        for (int s = 0; s < 8; ++s) {
            const float* q = part + (size_t)(s * 64 + lane) * 16;
#pragma unroll
            for (int e = 0; e < E_NUM; ++e) { sr[e] += q[e]; sn[e] += q[8 + e]; }
        }
        float nz[E_NUM];
        const float* np = noise + (size_t)t * E_NUM;
#pragma unroll
        for (int e = 0; e < E_NUM; ++e) {
            float s = sn[e];
            float sp = fmaxf(s, 0.f) + __logf(1.f + __expf(-fabsf(s)));
            nz[e] = sr[e] + np[e] * sp;
        }
        float v1 = -1e30f; int i1 = 0;
#pragma unroll
        for (int e = 0; e < E_NUM; ++e) if (nz[e] > v1) { v1 = nz[e]; i1 = e; }
        float v2 = -1e30f;
#pragma unroll
        for (int e = 0; e < E_NUM; ++e) if (e != i1 && nz[e] > v2) v2 = nz[e];
        gate[t] = 1.f / (1.f + __expf(v2 - v1));
#pragma unroll
        for (int e = 0; e < E_NUM; ++e) {
            unsigned long long m = __ballot(i1 == e);
            if (m == 0) continue;
            int cnum = __popcll(m);
            int leader = __ffsll((long long)m) - 1;
            int basec = 0;
            if (lane == leader) basec = atomicAdd(&cnt[e * CNT_PAD], cnum);
            basec = __shfl(basec, leader);
            if (i1 == e) {
                int pos = basec + __popcll(m & ((1ull << lane) - 1ull));
                if (pos < CAP) list[e * CAP + pos] = t;
            }
        }
    }
}

// ---------------- transpose batch: 18 32x32 tiles, 512 threads ----------------
__device__ __forceinline__ void transpose_batch(
    int tb, char* smem,
    const float* __restrict__ w1, u16* __restrict__ W1t,
    const float* __restrict__ w2, u16* __restrict__ W2t)
{
    float (*tile)[33] = (float(*)[33])smem;
    int tid = threadIdx.x;
    int tx = tid & 31, ty = tid >> 5;     // ty 0..15
    for (int it = 0; it < 18; ++it) {
        int b = tb * 18 + it;             // 0..9215
        int z = b / 576, rem = b % 576;
        int by = rem / 48, bx = rem % 48;
        const float* in; u16* out; int S, R, r0, c0;
        if (z < E_NUM) {
            in = w1 + (size_t)z * CDIM * DFF;  out = W1t + (size_t)z * CDIM * DFF;
            S = DFF; R = CDIM; c0 = bx * 32; r0 = by * 32;
        } else {
            in = w2 + (size_t)(z - E_NUM) * DFF * CDIM;
            out = W2t + (size_t)(z - E_NUM) * DFF * CDIM;
            S = CDIM; R = DFF; r0 = bx * 32; c0 = by * 32;
        }
#pragma unroll
        for (int i = ty; i < 32; i += 16)
            tile[i][tx] = in[(size_t)(r0 + i) * S + (c0 + tx)];
        __syncthreads();
#pragma unroll
        for (int i = ty; i < 32; i += 16)
            out[(size_t)(c0 + i) * R + (r0 + tx)] = f2bf(tile[tx][i]);
        __syncthreads();
    }
}

// ------------- FFN tile: R12's measured 512-thread GEMM body ----------------
template <int KD, int ND, bool FFN1>
__device__ __forceinline__ void ffn_tile(
    int tk, char* smem, int* s_tok,
    const u16* __restrict__ A, const u16* __restrict__ Bt,
    const float* __restrict__ bias, u16* __restrict__ H, float* __restrict__ Out,
    const int* __restrict__ cnt, const int* __restrict__ list,
    const float* __restrict__ gate, const u16* __restrict__ dummy)
{
    constexpr int NT = ND / 128;
    int n_idx = tk % NT;
    int mglob = tk / NT;                   // 0..511
    int e = mglob >> 6;
    int m0 = (mglob & 63) * 128;
    int base, n_e;
    expert_span(cnt, e, base, n_e);
    int pad_e = (n_e + 127) & ~127;
    if (m0 >= pad_e) return;               // uniform: no barrier divergence
    const u16* Be = Bt + ((size_t)e * ND + (size_t)n_idx * 128) * KD;

    u16* As0 = (u16*)smem;                 // 2 bufs x 16 KB
    u16* Bs0 = (u16*)(smem + 32768);       // 2 bufs x 16 KB

    int tid = threadIdx.x;
    int w = tid >> 6, lane = tid & 63;
    int quad = lane >> 4, l15 = lane & 15;
    int wr = w & 1;            // M half (64 rows)
    int wc = w >> 1;           // N quarter (32 cols)
    int srow = tid >> 3;       // 0..63
    int gcol = ((tid & 7) ^ (srow & 7)) * 8;

    if (FFN1) {
        if (tid < 128) {
            int rr = m0 + tid;
            s_tok[tid] = (rr < n_e) ? list[(size_t)e * CAP + rr] : -1;
        }
        __syncthreads();
    }
    const u16* Arow[2];
#pragma unroll
    for (int i = 0; i < 2; ++i) {
        int row = i * 64 + srow;
        if (FFN1) {
            int s = s_tok[row];
            Arow[i] = (s >= 0) ? A + (size_t)s * KD : dummy;
        } else {
            Arow[i] = A + (size_t)(base + m0 + row) * KD;
        }
    }

    auto stage = [&](int buf, int kb) {
#pragma unroll
        for (int i = 0; i < 2; ++i) {
            gload_lds16(Arow[i] + kb * 64 + gcol, &As0[buf * 8192 + i * 4096 + tid * 8]);
            gload_lds16(Be + (size_t)(i * 64 + srow) * KD + kb * 64 + gcol,
                        &Bs0[buf * 8192 + i * 4096 + tid * 8]);
        }
    };

    f32x4 acc[4][2];
    f32x4 zero = {0.f, 0.f, 0.f, 0.f};
#pragma unroll
    for (int a = 0; a < 4; ++a)
#pragma unroll
        for (int b = 0; b < 2; ++b) acc[a][b] = zero;

    constexpr int NK = KD / 64;
    stage(0, 0);
#pragma unroll 2
    for (int kb = 0; kb < NK; ++kb) {
        const int cur = kb & 1;
        if (kb + 1 < NK) {
            stage(cur ^ 1, kb + 1);
            asm volatile("s_waitcnt vmcnt(4)" ::: "memory");
        } else {
            asm volatile("s_waitcnt vmcnt(0)" ::: "memory");
        }
        __builtin_amdgcn_s_barrier();
        __builtin_amdgcn_sched_barrier(0);
#pragma unroll
        for (int h = 0; h < 2; ++h) {
            int pga = ((h * 4 + quad) ^ (l15 & 7)) * 8;
            short8 af[4], bf[2];
#pragma unroll
            for (int t = 0; t < 4; ++t)
                af[t] = *(const short8*)&As0[cur * 8192 + (wr * 64 + t * 16 + l15) * 64 + pga];
#pragma unroll
            for (int t = 0; t < 2; ++t)
                bf[t] = *(const short8*)&Bs0[cur * 8192 + (wc * 32 + t * 16 + l15) * 64 + pga];
#pragma unroll
            for (int mt = 0; mt < 4; ++mt)
#pragma unroll
                for (int nt = 0; nt < 2; ++nt)
                    acc[mt][nt] = __builtin_amdgcn_mfma_f32_16x16x32_bf16(
                        af[mt], bf[nt], acc[mt][nt], 0, 0, 0);
        }
        __builtin_amdgcn_sched_barrier(0);
        __builtin_amdgcn_s_barrier();
        __builtin_amdgcn_sched_barrier(0);
    }

    int n0 = n_idx * 128;
    if (FFN1) {
        u16* Hs = As0;   // 32 KB, K-loop done
#pragma unroll
        for (int mt = 0; mt < 4; ++mt) {
            int rowL = wr * 64 + mt * 16 + quad * 4;
#pragma unroll
            for (int nt = 0; nt < 2; ++nt) {
                int colL = wc * 32 + nt * 16 + l15;
                float b = bias[(size_t)e * ND + n0 + colL];
#pragma unroll
                for (int r = 0; r < 4; ++r) {
                    float v = acc[mt][nt][r] + b;
                    v = fmaxf(v, 0.f);
                    int row = rowL + r;
                    Hs[row * 128 + (colL ^ ((row & 7) << 3))] = f2bf(v * v);
                }
            }
        }
        __syncthreads();
        u16* He = H + (size_t)(base + m0) * ND + n0;
#pragma unroll
        for (int j = 0; j < 4; ++j) {
            int idx = tid + j * 512;
            int row = idx >> 4;
            int c8 = (idx & 15) * 8;
            *(f32x4*)(He + (size_t)row * ND + c8) =
                *(const f32x4*)(Hs + row * 128 + (c8 ^ ((row & 7) << 3)));
        }
    } else {
#pragma unroll
        for (int mt = 0; mt < 4; ++mt) {
            int rowL = wr * 64 + mt * 16 + quad * 4;
#pragma unroll
            for (int r = 0; r < 4; ++r) {
                int rr = m0 + rowL + r;
                if (rr < n_e) {
                    int tok = list[(size_t)e * CAP + rr];
                    float g = gate[tok];
#pragma unroll
                    for (int nt = 0; nt < 2; ++nt) {
                        int col = n0 + wc * 32 + nt * 16 + l15;
                        float v = acc[mt][nt][r] + bias[(size_t)e * ND + col];
                        Out[(size_t)tok * CDIM + col] = v * g;
                    }
                }
            }
        }
    }
    __syncthreads();   // safe LDS reuse by next tile
}

// ---------------- cooperative mega-kernel (R15) ----------------
// R14 post-mortem: hand-rolled atomic barrier hung (core dump after ~12s) —
// DIY cross-XCD release/acquire rejected. Same theory (60-75us of launch gaps,
// measured Σdispatch vs total in R8/R11/R12), sanctioned mechanism:
// hipLaunchCooperativeKernel + grid.sync() (runtime-validated residency and
// correct cross-XCD fences). 256 blocks x 512 thr, static work split.
struct MegaArgs {
    const float* x; const float* noise;
    const float* w_route; const float* b_route;
    const float* w_noise; const float* b_noise;
    const float* w1; const float* b1;
    const float* w2; const float* b2;
    int* cnt; int* list; float* gate; u16* xbf;
    u16* W1t; u16* W2t; u16* Hb; const u16* dummy; float* out;
};

__global__ __launch_bounds__(512, 2) void moe_coop(MegaArgs a)
{
    __shared__ __align__(16) char smem[65536];
    __shared__ int s_tok[128];
    int b = blockIdx.x;
    cg::grid_group grid = cg::this_grid();

    // ---- phase 0: routing (2 slices) + transposes (2 batches) ----
    routing_slice(b, smem, a.x, a.noise, a.w_route, a.b_route,
                  a.w_noise, a.b_noise, a.cnt, a.list, a.gate, a.xbf);
    __syncthreads();
    routing_slice(b + NBLK, smem, a.x, a.noise, a.w_route, a.b_route,
                  a.w_noise, a.b_noise, a.cnt, a.list, a.gate, a.xbf);
    __syncthreads();
    transpose_batch(b, smem, a.w1, a.W1t, a.w2, a.W2t);
    transpose_batch(b + NBLK, smem, a.w1, a.W1t, a.w2, a.W2t);

    grid.sync();

    // ---- phase 1: FFN1 (24 tiles/block) ----
    for (int t = b; t < FFN1_TILES; t += NBLK)
        ffn_tile<CDIM, DFF, true>(t, smem, s_tok, a.xbf, a.W1t, a.b1, a.Hb,
                                  nullptr, a.cnt, a.list, nullptr, a.dummy);

    grid.sync();

    // ---- phase 2: FFN2 (6 tiles/block) ----
    for (int t = b; t < FFN2_TILES; t += NBLK)
        ffn_tile<DFF, CDIM, false>(t, smem, s_tok, a.Hb, a.W2t, a.b2, nullptr,
                                   a.out, a.cnt, a.list, a.gate, nullptr);
}

extern "C" void kernel_launch(void* const* d_in, const int* in_sizes, int n_in,
                              void* d_out, int out_size, void* d_ws, size_t ws_size,
                              hipStream_t stream)
{
    const float* x       = (const float*)d_in[0];
    const float* noise   = (const float*)d_in[1];
    const float* w_route = (const float*)d_in[2];
    const float* b_route = (const float*)d_in[3];
    const float* w_noise = (const float*)d_in[4];
    const float* b_noise = (const float*)d_in[5];
    const float* w1      = (const float*)d_in[6];
    const float* b1      = (const float*)d_in[7];
    const float* w2      = (const float*)d_in[8];
    const float* b2      = (const float*)d_in[9];
    float* out = (float*)d_out;

    char* ws = (char*)d_ws;
    size_t off = 0;
    auto alloc = [&](size_t bytes) {
        char* p = ws + off;
        off += (bytes + 255) & ~(size_t)255;
        return p;
    };
    // zeroed prefix: cnt (2048) + dummy (1024), one memset
    int*   cnt   = (int*)alloc((size_t)E_NUM * CNT_PAD * sizeof(int));
    u16*   dummy = (u16*)alloc((size_t)CDIM * 2);
    size_t zspan = off;
    int*   list  = (int*)alloc((size_t)E_NUM * CAP * sizeof(int));
    float* gate  = (float*)alloc((size_t)NTOK * sizeof(float));
    u16*   W1t   = (u16*)alloc((size_t)E_NUM * DFF * CDIM * 2);
    u16*   W2t   = (u16*)alloc((size_t)E_NUM * CDIM * DFF * 2);
    u16*   Xbf   = (u16*)alloc((size_t)NTOK * CDIM * 2);
    size_t rows = NTOK + E_NUM * 128;  // packed-row bound
    u16*   Hb    = (u16*)alloc(rows * DFF * 2);

    hipMemsetAsync(ws, 0, zspan, stream);

    MegaArgs args = { x, noise, w_route, b_route, w_noise, b_noise,
                      w1, b1, w2, b2, cnt, list, gate, Xbf,
                      W1t, W2t, Hb, dummy, out };
    void* kparams[] = { &args };
    hipLaunchCooperativeKernel((const void*)moe_coop, dim3(NBLK), dim3(512),
                               kparams, 0, stream);
}